// Round 13
// baseline (80.932 us; speedup 1.0000x reference)
//
#include <hip/hip_runtime.h>
#include <hip/hip_bf16.h>

// B=8, T=2048, E=1024, H=64
// Round 13: proj rebuilt: x fragments -> REGISTERS (plain NT dwordx4, parity
// double-buffer, no barrier coupling); only W flows through the LDS ring
// (ring-3 x 24KB = 72KB, K-tile=64, 16 steps, 24 units staged 3/wave by all
// 8 waves, vmcnt(7) counted + 1 barrier/step). __launch_bounds__(512,4)
// targets <=128 VGPR -> 2 blocks/CU. attn/reduce/wprep identical to r12.
//
// Workspace: qb 2MB | kvb 4MB | partial 16MB | Wtb 384KB

typedef __attribute__((ext_vector_type(4))) float f32x4;
typedef __attribute__((ext_vector_type(4))) float float4_t;
typedef __attribute__((ext_vector_type(8))) short short8;
typedef __attribute__((ext_vector_type(4))) unsigned uint4_t;
typedef __attribute__((ext_vector_type(2))) unsigned uint2_t;

#define MFMA32(a, b, c) __builtin_amdgcn_mfma_f32_16x16x32_bf16(a, b, c, 0, 0, 0)

__device__ __forceinline__ short f2bf(float f) {
  unsigned u = __builtin_bit_cast(unsigned, f);
  unsigned r = (u + 0x7FFFu + ((u >> 16) & 1u)) >> 16;  // RNE
  return (short)r;
}

__device__ __forceinline__ unsigned cvt_pk_bf16(float lo, float hi) {
  unsigned r;
  asm volatile("v_cvt_pk_bf16_f32 %0, %1, %2" : "=v"(r) : "v"(lo), "v"(hi));
  return r;  // low16=bf16(lo), high16=bf16(hi)
}

__device__ __forceinline__ void gload16(const short* g, short* l) {
  __builtin_amdgcn_global_load_lds(
      (const __attribute__((address_space(1))) unsigned*)g,
      (__attribute__((address_space(3))) unsigned*)l, 16, 0, 0);
}

// ---------------- Kernel 0: W transpose+convert ----------------
// Wtb[n_global][k] bf16, n_global = wi*64 + n in [0,192), k in [0,1024)
__global__ __launch_bounds__(256) void wprep_kernel(
    const float* __restrict__ Wq, const float* __restrict__ Wk,
    const float* __restrict__ Wv, short* __restrict__ Wtb) {
  int lin = blockIdx.x * 256 + threadIdx.x;  // 24576 threads
  int n = lin & 63;
  int k8 = (lin >> 6) & 127;
  int wi = lin >> 13;
  const float* W = (wi == 0) ? Wq : (wi == 1) ? Wk : Wv;
  short* dst = Wtb + wi * 65536 + n * 1024 + k8 * 8;
#pragma unroll
  for (int i = 0; i < 8; i++) dst[i] = f2bf(W[(k8 * 8 + i) * 64 + n]);
}

// ---------------- Kernel 1: pipelined QKV projection ----------------
// 256 blocks x 512 thr (8 waves). M=64/block, K-tile=64, 16 steps.
// W LDS tile = 24 units x 1KB: unit u = cf*2+ks (cf=0..11, ks=0..1);
//   lane l holds Wtb[cf*16+(l&15)][k0+ks*32+8*(l>>4) .. +7].
// x: REGISTERS. Wave (wr=w&3, wc=w>>2) covers rows m0+wr*16+lr, cols wc*96..+95.
// Per tile: 4 NT dwordx4 at k0+g*8+{0,4,32,36} floats -> cvt -> a-frags.
// Both operands share k-bijection k = ks*32 + 8g + j -> contraction exact.
__device__ __forceinline__ void stage_W(const short* __restrict__ Wtb,
                                        short* dst, int k0, int w, int l) {
  const int g = l >> 4, lr = l & 15;
#pragma unroll
  for (int i = 0; i < 3; i++) {
    int u = w * 3 + i;  // 0..23
    int cf = u >> 1, ks = u & 1;
    const short* src = Wtb + (cf * 16 + lr) * 1024 + k0 + ks * 32 + g * 8;
    gload16(src, dst + u * 512);
  }
}

__device__ __forceinline__ void load_x(const float* __restrict__ xbase, int k0,
                                       f32x4 (&xb)[4]) {
  xb[0] = __builtin_nontemporal_load((const float4_t*)(xbase + k0));
  xb[1] = __builtin_nontemporal_load((const float4_t*)(xbase + k0 + 4));
  xb[2] = __builtin_nontemporal_load((const float4_t*)(xbase + k0 + 32));
  xb[3] = __builtin_nontemporal_load((const float4_t*)(xbase + k0 + 36));
}

__device__ __forceinline__ void proj_compute(const short* __restrict__ ldsb,
                                             const f32x4 (&xb)[4],
                                             f32x4 (&acc)[6], int wc, int l) {
#pragma unroll
  for (int ks = 0; ks < 2; ks++) {
    uint4_t u_;
    u_[0] = cvt_pk_bf16(xb[ks * 2][0], xb[ks * 2][1]);
    u_[1] = cvt_pk_bf16(xb[ks * 2][2], xb[ks * 2][3]);
    u_[2] = cvt_pk_bf16(xb[ks * 2 + 1][0], xb[ks * 2 + 1][1]);
    u_[3] = cvt_pk_bf16(xb[ks * 2 + 1][2], xb[ks * 2 + 1][3]);
    short8 a = __builtin_bit_cast(short8, u_);
#pragma unroll
    for (int nf = 0; nf < 6; nf++) {
      int cf = wc * 6 + nf;
      short8 bfrag = *(const short8*)&ldsb[(cf * 2 + ks) * 512 + l * 8];
      acc[nf] = MFMA32(a, bfrag, acc[nf]);
    }
  }
}

template <int I>
__device__ __forceinline__ void proj_step(const float* __restrict__ xbase,
                                          const short* __restrict__ Wtb, short* lds,
                                          f32x4 (&xb0)[4], f32x4 (&xb1)[4],
                                          f32x4 (&acc)[6], int w, int wc, int l) {
  // At top: outstanding = W(I+1):3 + x(I):4 (+unretired W(I)) -> vmcnt(7)
  // guarantees W(I) landed. Tail I=15: x(I) only -> vmcnt(4) covers W15.
  constexpr int NW = (I == 15) ? 4 : 7;
  __builtin_amdgcn_sched_barrier(0);
  asm volatile("s_waitcnt vmcnt(%0)" ::"n"(NW) : "memory");
  __builtin_amdgcn_s_barrier();  // all waves: W(I) ready, W buf (I+2)%3 free
  __builtin_amdgcn_sched_barrier(0);
  if constexpr (I + 2 < 16) stage_W(Wtb, lds + ((I + 2) % 3) * 12288, (I + 2) * 64, w, l);
  if constexpr (I + 1 < 16) {
    if constexpr ((I & 1) == 0) load_x(xbase, (I + 1) * 64, xb1);
    else                        load_x(xbase, (I + 1) * 64, xb0);
  }
  if constexpr ((I & 1) == 0) proj_compute(lds + (I % 3) * 12288, xb0, acc, wc, l);
  else                        proj_compute(lds + (I % 3) * 12288, xb1, acc, wc, l);
}

__global__ __launch_bounds__(512, 4) void proj_kernel(
    const float* __restrict__ x, const short* __restrict__ Wtb,
    short* __restrict__ qb, short* __restrict__ kvb) {
  __shared__ __align__(16) short lds[3 * 24 * 512];  // 72KB ring-3 (W only)
  const int tid = threadIdx.x;
  const int l = tid & 63, w = tid >> 6;
  const int g = l >> 4, lr = l & 15;
  const int wr = w & 3, wc = w >> 2;
  const int m0 = blockIdx.x * 64;
  const float* xbase = x + (size_t)(m0 + wr * 16 + lr) * 1024 + g * 8;

  f32x4 acc[6];
#pragma unroll
  for (int i = 0; i < 6; i++) acc[i] = (f32x4){0.f, 0.f, 0.f, 0.f};

  f32x4 xb0[4], xb1[4];
  // prologue: W tiles 0,1 staged; x tile 0 in regs
  stage_W(Wtb, lds, 0, w, l);
  stage_W(Wtb, lds + 12288, 64, w, l);
  load_x(xbase, 0, xb0);

  proj_step<0>(xbase, Wtb, lds, xb0, xb1, acc, w, wc, l);
  proj_step<1>(xbase, Wtb, lds, xb0, xb1, acc, w, wc, l);
  proj_step<2>(xbase, Wtb, lds, xb0, xb1, acc, w, wc, l);
  proj_step<3>(xbase, Wtb, lds, xb0, xb1, acc, w, wc, l);
  proj_step<4>(xbase, Wtb, lds, xb0, xb1, acc, w, wc, l);
  proj_step<5>(xbase, Wtb, lds, xb0, xb1, acc, w, wc, l);
  proj_step<6>(xbase, Wtb, lds, xb0, xb1, acc, w, wc, l);
  proj_step<7>(xbase, Wtb, lds, xb0, xb1, acc, w, wc, l);
  proj_step<8>(xbase, Wtb, lds, xb0, xb1, acc, w, wc, l);
  proj_step<9>(xbase, Wtb, lds, xb0, xb1, acc, w, wc, l);
  proj_step<10>(xbase, Wtb, lds, xb0, xb1, acc, w, wc, l);
  proj_step<11>(xbase, Wtb, lds, xb0, xb1, acc, w, wc, l);
  proj_step<12>(xbase, Wtb, lds, xb0, xb1, acc, w, wc, l);
  proj_step<13>(xbase, Wtb, lds, xb0, xb1, acc, w, wc, l);
  proj_step<14>(xbase, Wtb, lds, xb0, xb1, acc, w, wc, l);
  proj_step<15>(xbase, Wtb, lds, xb0, xb1, acc, w, wc, l);

  // epilogue: verified store formulas (wave = 16 rows x 96 cols)
#pragma unroll
  for (int nf = 0; nf < 6; nf++) {
    int colg0 = wc * 96 + nf * 16;
    int wi = colg0 >> 6;
    int d = (colg0 & 63) + lr;
    // fold 1/sqrt(H)*log2(e) into q so attn softmax uses 2^x directly
    float scale = (wi == 0) ? 0.18033688f : 1.0f;
#pragma unroll
    for (int r = 0; r < 4; r++) {
      int row = m0 + wr * 16 + g * 4 + r;
      int b = row >> 11, t = row & 2047;
      short bv = f2bf(acc[nf][r] * scale);
      if (wi == 0) {
        int idx = (((b * 128 + (t >> 4)) * 2 + (d >> 5)) * 64 +
                   ((((d >> 3) & 3) << 4) | (t & 15))) * 8 + (d & 7);
        qb[idx] = bv;
      } else if (wi == 1) {
        int u = (b << 2) | (((t >> 4) & 1) << 1) | (d >> 5);
        int idx = (((t >> 5) * 64 + u) << 9) +
                  ((((((d >> 3) & 3) << 4)) | (t & 15)) << 3) + (d & 7);
        kvb[idx] = bv;
      } else {
        int u = 32 + (b << 2) + (d >> 4);
        int idx = (((t >> 5) * 64 + u) << 9) +
                  (((((t >> 2) & 3) << 4) | (d & 15)) << 3) + (((t >> 4) & 1) << 2) + (t & 3);
        kvb[idx] = bv;
      }
    }
  }
}

// ---------------- Kernel 2: pipelined fused attention ----------------
__device__ __forceinline__ void stage_step(const short* __restrict__ kvb,
                                           short* lds_buf, int w, int l, int W) {
#pragma unroll
  for (int i = 0; i < 8; i++) {
    int u = w * 8 + i;
    const short* src = kvb + (((size_t)W * 64 + u) << 9) + l * 8;
    gload16(src, lds_buf + u * 512);
  }
}

// 256 blocks x 512 thr = 8 waves: tt = w>>1 (4 t-tiles of 16), dh = w&1.
// Block: 64 t-rows x one 256-s chunk; 8 steps of 32 s. sc = xcd (lin&7).
__global__ __launch_bounds__(512, 2) void attn_kernel(
    const short* __restrict__ qb, const short* __restrict__ kvb,
    short* __restrict__ partial) {
  __shared__ __align__(16) short lds[2][64 * 512];  // 2 x 64KB ring
  const int tid = threadIdx.x;
  const int l = tid & 63, w = tid >> 6;
  const int tt = w >> 1, dh = w & 1;
  const int lin = blockIdx.x;     // 0..255
  const int sc = lin & 7;         // 0..7: per-XCD s-chunk of 256
  const int tblk = lin >> 3;      // 0..31
  const int tb16 = tblk * 4 + tt; // 0..127

  // Q hoisted: 16 x b128
  short8 qf[8][2];
#pragma unroll
  for (int b = 0; b < 8; b++)
#pragma unroll
    for (int ks = 0; ks < 2; ks++)
      qf[b][ks] = *(const short8*)&qb[(size_t)((b * 128 + tb16) * 2 + ks) * 512 + l * 8];

  f32x4 oacc[8][2];
#pragma unroll
  for (int b = 0; b < 8; b++)
#pragma unroll
    for (int n = 0; n < 2; n++) oacc[b][n] = (f32x4){0.f, 0.f, 0.f, 0.f};

  stage_step(kvb, &lds[0][0], w, l, sc * 8);

  for (int it = 0; it < 8; it++) {
    __syncthreads();  // drains step-old staging (free), publishes buf[it]
    if (it + 1 < 8) stage_step(kvb, &lds[(it + 1) & 1][0], w, l, sc * 8 + it + 1);
    const short* ldsc = &lds[it & 1][0];

    uint2_t plo[8], phi[8];
#pragma unroll
    for (int sf = 0; sf < 2; sf++) {
      f32x4 S[8];
      __builtin_amdgcn_s_setprio(1);
#pragma unroll
      for (int b = 0; b < 8; b++) {
        short8 kf0 = *(const short8*)&ldsc[(b * 4 + sf * 2 + 0) * 512 + l * 8];
        short8 kf1 = *(const short8*)&ldsc[(b * 4 + sf * 2 + 1) * 512 + l * 8];
        f32x4 s = (f32x4){0.f, 0.f, 0.f, 0.f};
        s = MFMA32(kf0, qf[b][0], s);
        s = MFMA32(kf1, qf[b][1], s);
        S[b] = s;
      }
      __builtin_amdgcn_s_setprio(0);
      // softmax over batch (elementwise across the 8 register sets)
#pragma unroll
      for (int r = 0; r < 4; r++) {
        float den = 0.f;
#pragma unroll
        for (int b = 0; b < 8; b++) {
          float e = __builtin_amdgcn_exp2f(S[b][r]);
          S[b][r] = e;
          den += e;
        }
        float inv = __builtin_amdgcn_rcpf(den);
#pragma unroll
        for (int b = 0; b < 8; b++) S[b][r] *= inv;
      }
#pragma unroll
      for (int b = 0; b < 8; b++) {
        uint2_t pw;
        pw[0] = cvt_pk_bf16(S[b][0], S[b][1]);
        pw[1] = cvt_pk_bf16(S[b][2], S[b][3]);
        if (sf == 0) plo[b] = pw; else phi[b] = pw;
      }
    }
    // PV k=32: A = V unit (16 d x 32 s, sigma-map), B = packed P
    __builtin_amdgcn_s_setprio(1);
#pragma unroll
    for (int b = 0; b < 8; b++) {
      uint4_t pu;
      pu[0] = plo[b][0]; pu[1] = plo[b][1]; pu[2] = phi[b][0]; pu[3] = phi[b][1];
      short8 pbv = __builtin_bit_cast(short8, pu);
      short8 vf0 = *(const short8*)&ldsc[(32 + b * 4 + dh * 2 + 0) * 512 + l * 8];
      short8 vf1 = *(const short8*)&ldsc[(32 + b * 4 + dh * 2 + 1) * 512 + l * 8];
      oacc[b][0] = MFMA32(vf0, pbv, oacc[b][0]);
      oacc[b][1] = MFMA32(vf1, pbv, oacc[b][1]);
    }
    __builtin_amdgcn_s_setprio(0);
  }

  // store bf16 partial fragment-major (uint2/lane, wave-contiguous 512B runs)
  uint2_t* pout = (uint2_t*)partial;
#pragma unroll
  for (int b = 0; b < 8; b++)
#pragma unroll
    for (int n = 0; n < 2; n++) {
      int df = dh * 2 + n;
      uint2_t pk;
      pk[0] = cvt_pk_bf16(oacc[b][n][0], oacc[b][n][1]);
      pk[1] = cvt_pk_bf16(oacc[b][n][2], oacc[b][n][3]);
      __builtin_nontemporal_store(
          pk, &pout[(size_t)(((sc * 8 + b) * 128 + tb16) * 4 + df) * 64 + l]);
    }
}

// ---------------- Kernel 3: reduce bf16 partials -> f32 out ----------------
__global__ __launch_bounds__(256) void reduce_kernel(const short* __restrict__ partial,
                                                     float* __restrict__ out) {
  int i = blockIdx.x * 256 + threadIdx.x;  // 0..262143: (b,tb16,df,l)
  const uint2_t* p = (const uint2_t*)partial;
  float4_t a = (float4_t){0.f, 0.f, 0.f, 0.f};
  for (int sc = 0; sc < 8; sc++) {
    uint2_t v = __builtin_nontemporal_load(&p[(size_t)sc * 262144 + i]);
    a[0] += __builtin_bit_cast(float, v[0] << 16);
    a[1] += __builtin_bit_cast(float, v[0] & 0xFFFF0000u);
    a[2] += __builtin_bit_cast(float, v[1] << 16);
    a[3] += __builtin_bit_cast(float, v[1] & 0xFFFF0000u);
  }
  int b = i >> 15;
  int r1 = i & 32767;
  int tb16 = r1 >> 8;
  int r2 = r1 & 255;
  int df = r2 >> 6;
  int ll = r2 & 63;
  int gg = ll >> 4, lrr = ll & 15;
  *(float4_t*)&out[(size_t)(b * 2048 + tb16 * 16 + lrr) * 64 + df * 16 + gg * 4] = a;
}

extern "C" void kernel_launch(void* const* d_in, const int* in_sizes, int n_in,
                              void* d_out, int out_size, void* d_ws, size_t ws_size,
                              hipStream_t stream) {
  const float* x = (const float*)d_in[0];
  const float* Wq = (const float*)d_in[1];
  const float* Wk = (const float*)d_in[2];
  const float* Wv = (const float*)d_in[3];
  float* out = (float*)d_out;

  char* ws = (char*)d_ws;
  short* qb = (short*)ws;                     // 2MB
  short* kvb = qb + 16384 * 64;               // 4MB (64 windows x 64 units)
  short* partial = kvb + 2 * 16384 * 64;      // 16MB bf16 fragment-major
  short* Wtb = partial + 8ull * 262144 * 4;   // 384KB

  wprep_kernel<<<96, 256, 0, stream>>>(Wq, Wk, Wv, Wtb);
  proj_kernel<<<256, 512, 0, stream>>>(x, Wtb, qb, kvb);
  attn_kernel<<<256, 512, 0, stream>>>(qb, kvb, partial);
  reduce_kernel<<<1024, 256, 0, stream>>>(partial, out);
}

// Round 14
// 63.311 us; speedup vs baseline: 1.2783x; 1.2783x over previous
//
#include <hip/hip_runtime.h>
#include <hip/hip_bf16.h>

// B=8, T=2048, E=1024, H=64
// Round 14: exact r12 (best, 62.76us) with ONE change: the partial buffer
// handoff attn->reduce no longer uses non-temporal hints (NT bypasses
// L2/L3 -> 32MB of HBM round-trip). Plain stores/loads let L2/L3 serve it.
// NT kept only on the final `out` store (never re-read).
//
// Workspace: qb 2MB | kvb 4MB | partial 16MB | Wtb 384KB

typedef __attribute__((ext_vector_type(4))) float f32x4;
typedef __attribute__((ext_vector_type(4))) float float4_t;
typedef __attribute__((ext_vector_type(8))) short short8;
typedef __attribute__((ext_vector_type(4))) unsigned uint4_t;
typedef __attribute__((ext_vector_type(2))) unsigned uint2_t;

#define MFMA32(a, b, c) __builtin_amdgcn_mfma_f32_16x16x32_bf16(a, b, c, 0, 0, 0)

__device__ __forceinline__ short f2bf(float f) {
  unsigned u = __builtin_bit_cast(unsigned, f);
  unsigned r = (u + 0x7FFFu + ((u >> 16) & 1u)) >> 16;  // RNE
  return (short)r;
}

__device__ __forceinline__ unsigned cvt_pk_bf16(float lo, float hi) {
  unsigned r;
  asm volatile("v_cvt_pk_bf16_f32 %0, %1, %2" : "=v"(r) : "v"(lo), "v"(hi));
  return r;  // low16=bf16(lo), high16=bf16(hi)
}

__device__ __forceinline__ void gload16(const short* g, short* l) {
  __builtin_amdgcn_global_load_lds(
      (const __attribute__((address_space(1))) unsigned*)g,
      (__attribute__((address_space(3))) unsigned*)l, 16, 0, 0);
}

// ---------------- Kernel 0: W transpose+convert ----------------
// Wtb[n_global][k] bf16, n_global = wi*64 + n in [0,192), k in [0,1024)
__global__ __launch_bounds__(256) void wprep_kernel(
    const float* __restrict__ Wq, const float* __restrict__ Wk,
    const float* __restrict__ Wv, short* __restrict__ Wtb) {
  int lin = blockIdx.x * 256 + threadIdx.x;  // 24576 threads
  int n = lin & 63;
  int k8 = (lin >> 6) & 127;
  int wi = lin >> 13;
  const float* W = (wi == 0) ? Wq : (wi == 1) ? Wk : Wv;
  short* dst = Wtb + wi * 65536 + n * 1024 + k8 * 8;
#pragma unroll
  for (int i = 0; i < 8; i++) dst[i] = f2bf(W[(k8 * 8 + i) * 64 + n]);
}

// ---------------- Kernel 1: pipelined QKV projection ----------------
// 256 blocks x 512 thr (8 waves). M=64 rows/block, K-tile=32, ring-4 80KB.
// LDS tile = 20 units x 1KB:
//   u<8  : x units (f32), u = xwr*2 + h; lane l holds
//          x[m0+xwr*16+(l&15)][k0 + 8*(l>>4) + 4h .. +3]
//   u>=8 : W units (bf16), u = 8 + cf (cf=0..11); lane l holds
//          Wtb[cf*16+(l&15)][k0 + 8*(l>>4) .. +7]
// Wave (wr=w&3, wc=w>>2): 16 rows x 96 cols, acc[6]. Both operands use the
// same within-tile k-bijection (k = 8g + j) -> contraction exact.
__device__ __forceinline__ void proj_stage(const float* __restrict__ x,
                                           const short* __restrict__ Wtb,
                                           short* dst, int m0, int k0, int w, int l) {
  const int g = l >> 4, lr = l & 15;
  if (w < 4) {
#pragma unroll
    for (int i = 0; i < 5; i++) {
      int u = w * 5 + i;
      if (u < 8) {
        int xwr = u >> 1, h = u & 1;
        const float* src = x + (size_t)(m0 + xwr * 16 + lr) * 1024 + k0 + g * 8 + h * 4;
        gload16((const short*)src, dst + u * 512);
      } else {
        int cf = u - 8;
        const short* src = Wtb + (cf * 16 + lr) * 1024 + k0 + g * 8;
        gload16(src, dst + u * 512);
      }
    }
  }
}

__device__ __forceinline__ void proj_compute(const short* __restrict__ ldsb,
                                             f32x4 (&acc)[6], int wr, int wc, int l) {
  f32x4 fa = *(const f32x4*)&ldsb[(wr * 2 + 0) * 512 + l * 8];  // k slots g*8+0..3
  f32x4 fb = *(const f32x4*)&ldsb[(wr * 2 + 1) * 512 + l * 8];  // k slots g*8+4..7
  uint4_t u_;
  u_[0] = cvt_pk_bf16(fa[0], fa[1]);
  u_[1] = cvt_pk_bf16(fa[2], fa[3]);
  u_[2] = cvt_pk_bf16(fb[0], fb[1]);
  u_[3] = cvt_pk_bf16(fb[2], fb[3]);
  short8 a = __builtin_bit_cast(short8, u_);
#pragma unroll
  for (int nf = 0; nf < 6; nf++) {
    int cf = wc * 6 + nf;
    short8 bfrag = *(const short8*)&ldsb[(8 + cf) * 512 + l * 8];
    acc[nf] = MFMA32(a, bfrag, acc[nf]);
  }
}

__global__ __launch_bounds__(512) void proj_kernel(
    const float* __restrict__ x, const short* __restrict__ Wtb,
    short* __restrict__ qb, short* __restrict__ kvb) {
  __shared__ __align__(16) short lds[4 * 20 * 512];  // 80KB ring-4
  const int tid = threadIdx.x;
  const int l = tid & 63, w = tid >> 6;
  const int g = l >> 4, lr = l & 15;
  const int wr = w & 3, wc = w >> 2;
  const int m0 = blockIdx.x * 64;

  f32x4 acc[6];
#pragma unroll
  for (int i = 0; i < 6; i++) acc[i] = (f32x4){0.f, 0.f, 0.f, 0.f};

  short* b0 = lds;
  short* b1 = lds + 10240;
  short* b2 = lds + 20480;
  short* b3 = lds + 30720;
  // prologue: 3 tiles in flight (15 loads/wave for w<4)
  proj_stage(x, Wtb, b0, m0, 0, w, l);
  proj_stage(x, Wtb, b1, m0, 32, w, l);
  proj_stage(x, Wtb, b2, m0, 64, w, l);

  for (int I = 0; I < 30; I++) {
    // outstanding/wave (w<4) at top: rem(I) + 5(I+1) + 5(I+2) ->
    // vmcnt(10) == tile I landed; never 0 mid-loop.
    asm volatile("s_waitcnt vmcnt(10)" ::: "memory");
    __builtin_amdgcn_s_barrier();
    __builtin_amdgcn_sched_barrier(0);
    if (I + 3 < 32) proj_stage(x, Wtb, b3, m0, (I + 3) * 32, w, l);
    proj_compute(b0, acc, wr, wc, l);
    short* t = b0; b0 = b1; b1 = b2; b2 = b3; b3 = t;
  }
  // I=30: only tile 31's 5 loads younger -> vmcnt(5) == tile 30 landed
  asm volatile("s_waitcnt vmcnt(5)" ::: "memory");
  __builtin_amdgcn_s_barrier();
  __builtin_amdgcn_sched_barrier(0);
  proj_compute(b0, acc, wr, wc, l);
  { short* t = b0; b0 = b1; b1 = b2; b2 = b3; b3 = t; }
  // I=31: drain
  asm volatile("s_waitcnt vmcnt(0)" ::: "memory");
  __builtin_amdgcn_s_barrier();
  __builtin_amdgcn_sched_barrier(0);
  proj_compute(b0, acc, wr, wc, l);

  // epilogue: verified store formulas (wave = 16 rows x 96 cols)
#pragma unroll
  for (int nf = 0; nf < 6; nf++) {
    int colg0 = wc * 96 + nf * 16;
    int wi = colg0 >> 6;
    int d = (colg0 & 63) + lr;
    // fold 1/sqrt(H)*log2(e) into q so attn softmax uses 2^x directly
    float scale = (wi == 0) ? 0.18033688f : 1.0f;
#pragma unroll
    for (int r = 0; r < 4; r++) {
      int row = m0 + wr * 16 + g * 4 + r;
      int b = row >> 11, t = row & 2047;
      short bv = f2bf(acc[nf][r] * scale);
      if (wi == 0) {
        int idx = (((b * 128 + (t >> 4)) * 2 + (d >> 5)) * 64 +
                   ((((d >> 3) & 3) << 4) | (t & 15))) * 8 + (d & 7);
        qb[idx] = bv;
      } else if (wi == 1) {
        int u = (b << 2) | (((t >> 4) & 1) << 1) | (d >> 5);
        int idx = (((t >> 5) * 64 + u) << 9) +
                  ((((((d >> 3) & 3) << 4)) | (t & 15)) << 3) + (d & 7);
        kvb[idx] = bv;
      } else {
        int u = 32 + (b << 2) + (d >> 4);
        int idx = (((t >> 5) * 64 + u) << 9) +
                  (((((t >> 2) & 3) << 4) | (d & 15)) << 3) + (((t >> 4) & 1) << 2) + (t & 3);
        kvb[idx] = bv;
      }
    }
  }
}

// ---------------- Kernel 2: pipelined fused attention ----------------
__device__ __forceinline__ void stage_step(const short* __restrict__ kvb,
                                           short* lds_buf, int w, int l, int W) {
#pragma unroll
  for (int i = 0; i < 8; i++) {
    int u = w * 8 + i;
    const short* src = kvb + (((size_t)W * 64 + u) << 9) + l * 8;
    gload16(src, lds_buf + u * 512);
  }
}

// 256 blocks x 512 thr = 8 waves: tt = w>>1 (4 t-tiles of 16), dh = w&1.
// Block: 64 t-rows x one 256-s chunk; 8 steps of 32 s. sc = xcd (lin&7).
__global__ __launch_bounds__(512, 2) void attn_kernel(
    const short* __restrict__ qb, const short* __restrict__ kvb,
    short* __restrict__ partial) {
  __shared__ __align__(16) short lds[2][64 * 512];  // 2 x 64KB ring
  const int tid = threadIdx.x;
  const int l = tid & 63, w = tid >> 6;
  const int tt = w >> 1, dh = w & 1;
  const int lin = blockIdx.x;     // 0..255
  const int sc = lin & 7;         // 0..7: per-XCD s-chunk of 256
  const int tblk = lin >> 3;      // 0..31
  const int tb16 = tblk * 4 + tt; // 0..127

  // Q hoisted: 16 x b128
  short8 qf[8][2];
#pragma unroll
  for (int b = 0; b < 8; b++)
#pragma unroll
    for (int ks = 0; ks < 2; ks++)
      qf[b][ks] = *(const short8*)&qb[(size_t)((b * 128 + tb16) * 2 + ks) * 512 + l * 8];

  f32x4 oacc[8][2];
#pragma unroll
  for (int b = 0; b < 8; b++)
#pragma unroll
    for (int n = 0; n < 2; n++) oacc[b][n] = (f32x4){0.f, 0.f, 0.f, 0.f};

  stage_step(kvb, &lds[0][0], w, l, sc * 8);

  for (int it = 0; it < 8; it++) {
    __syncthreads();  // drains step-old staging (free), publishes buf[it]
    if (it + 1 < 8) stage_step(kvb, &lds[(it + 1) & 1][0], w, l, sc * 8 + it + 1);
    const short* ldsc = &lds[it & 1][0];

    uint2_t plo[8], phi[8];
#pragma unroll
    for (int sf = 0; sf < 2; sf++) {
      f32x4 S[8];
      __builtin_amdgcn_s_setprio(1);
#pragma unroll
      for (int b = 0; b < 8; b++) {
        short8 kf0 = *(const short8*)&ldsc[(b * 4 + sf * 2 + 0) * 512 + l * 8];
        short8 kf1 = *(const short8*)&ldsc[(b * 4 + sf * 2 + 1) * 512 + l * 8];
        f32x4 s = (f32x4){0.f, 0.f, 0.f, 0.f};
        s = MFMA32(kf0, qf[b][0], s);
        s = MFMA32(kf1, qf[b][1], s);
        S[b] = s;
      }
      __builtin_amdgcn_s_setprio(0);
      // softmax over batch (elementwise across the 8 register sets)
#pragma unroll
      for (int r = 0; r < 4; r++) {
        float den = 0.f;
#pragma unroll
        for (int b = 0; b < 8; b++) {
          float e = __builtin_amdgcn_exp2f(S[b][r]);
          S[b][r] = e;
          den += e;
        }
        float inv = __builtin_amdgcn_rcpf(den);
#pragma unroll
        for (int b = 0; b < 8; b++) S[b][r] *= inv;
      }
#pragma unroll
      for (int b = 0; b < 8; b++) {
        uint2_t pw;
        pw[0] = cvt_pk_bf16(S[b][0], S[b][1]);
        pw[1] = cvt_pk_bf16(S[b][2], S[b][3]);
        if (sf == 0) plo[b] = pw; else phi[b] = pw;
      }
    }
    // PV k=32: A = V unit (16 d x 32 s, sigma-map), B = packed P
    __builtin_amdgcn_s_setprio(1);
#pragma unroll
    for (int b = 0; b < 8; b++) {
      uint4_t pu;
      pu[0] = plo[b][0]; pu[1] = plo[b][1]; pu[2] = phi[b][0]; pu[3] = phi[b][1];
      short8 pbv = __builtin_bit_cast(short8, pu);
      short8 vf0 = *(const short8*)&ldsc[(32 + b * 4 + dh * 2 + 0) * 512 + l * 8];
      short8 vf1 = *(const short8*)&ldsc[(32 + b * 4 + dh * 2 + 1) * 512 + l * 8];
      oacc[b][0] = MFMA32(vf0, pbv, oacc[b][0]);
      oacc[b][1] = MFMA32(vf1, pbv, oacc[b][1]);
    }
    __builtin_amdgcn_s_setprio(0);
  }

  // store bf16 partial fragment-major (uint2/lane, wave-contiguous 512B runs)
  // PLAIN stores: keep the producer->consumer handoff in L2/L3, not HBM.
  uint2_t* pout = (uint2_t*)partial;
#pragma unroll
  for (int b = 0; b < 8; b++)
#pragma unroll
    for (int n = 0; n < 2; n++) {
      int df = dh * 2 + n;
      uint2_t pk;
      pk[0] = cvt_pk_bf16(oacc[b][n][0], oacc[b][n][1]);
      pk[1] = cvt_pk_bf16(oacc[b][n][2], oacc[b][n][3]);
      pout[(size_t)(((sc * 8 + b) * 128 + tb16) * 4 + df) * 64 + l] = pk;
    }
}

// ---------------- Kernel 3: reduce bf16 partials -> f32 out ----------------
__global__ __launch_bounds__(256) void reduce_kernel(const short* __restrict__ partial,
                                                     float* __restrict__ out) {
  int i = blockIdx.x * 256 + threadIdx.x;  // 0..262143: (b,tb16,df,l)
  const uint2_t* p = (const uint2_t*)partial;
  float4_t a = (float4_t){0.f, 0.f, 0.f, 0.f};
  for (int sc = 0; sc < 8; sc++) {
    uint2_t v = p[(size_t)sc * 262144 + i];  // plain load: L2/L3-served
    a[0] += __builtin_bit_cast(float, v[0] << 16);
    a[1] += __builtin_bit_cast(float, v[0] & 0xFFFF0000u);
    a[2] += __builtin_bit_cast(float, v[1] << 16);
    a[3] += __builtin_bit_cast(float, v[1] & 0xFFFF0000u);
  }
  int b = i >> 15;
  int r1 = i & 32767;
  int tb16 = r1 >> 8;
  int r2 = r1 & 255;
  int df = r2 >> 6;
  int ll = r2 & 63;
  int gg = ll >> 4, lrr = ll & 15;
  float4_t o = a;
  __builtin_nontemporal_store(
      o, (float4_t*)&out[(size_t)(b * 2048 + tb16 * 16 + lrr) * 64 + df * 16 + gg * 4]);
}

extern "C" void kernel_launch(void* const* d_in, const int* in_sizes, int n_in,
                              void* d_out, int out_size, void* d_ws, size_t ws_size,
                              hipStream_t stream) {
  const float* x = (const float*)d_in[0];
  const float* Wq = (const float*)d_in[1];
  const float* Wk = (const float*)d_in[2];
  const float* Wv = (const float*)d_in[3];
  float* out = (float*)d_out;

  char* ws = (char*)d_ws;
  short* qb = (short*)ws;                     // 2MB
  short* kvb = qb + 16384 * 64;               // 4MB (64 windows x 64 units)
  short* partial = kvb + 2 * 16384 * 64;      // 16MB bf16 fragment-major
  short* Wtb = partial + 8ull * 262144 * 4;   // 384KB

  wprep_kernel<<<96, 256, 0, stream>>>(Wq, Wk, Wv, Wtb);
  proj_kernel<<<256, 512, 0, stream>>>(x, Wtb, qb, kvb);
  attn_kernel<<<256, 512, 0, stream>>>(qb, kvb, partial);
  reduce_kernel<<<1024, 256, 0, stream>>>(partial, out);
}

// Round 15
// 57.563 us; speedup vs baseline: 1.4060x; 1.0999x over previous
//
#include <hip/hip_runtime.h>
#include <hip/hip_bf16.h>

// B=8, T=2048, E=1024, H=64
// Round 15: r14 with ONE change: Wtb is stored unit-fragment-major
// ([ktile][cf][lane][8] bf16), so every W global_load_lds in proj is a
// linear 1KB run (8 fully-used cache lines) instead of a 16-row x 64B
// scatter (16-32 half-used lines). Kills ~60% of proj's per-step L2
// transactions. wprep gather cost unchanged (store order only).
// proj pipeline / vmcnt arithmetic / attn / reduce byte-identical to r14.
//
// Workspace: qb 2MB | kvb 4MB | partial 16MB | Wtb 384KB

typedef __attribute__((ext_vector_type(4))) float f32x4;
typedef __attribute__((ext_vector_type(4))) float float4_t;
typedef __attribute__((ext_vector_type(8))) short short8;
typedef __attribute__((ext_vector_type(4))) unsigned uint4_t;
typedef __attribute__((ext_vector_type(2))) unsigned uint2_t;

#define MFMA32(a, b, c) __builtin_amdgcn_mfma_f32_16x16x32_bf16(a, b, c, 0, 0, 0)

__device__ __forceinline__ short f2bf(float f) {
  unsigned u = __builtin_bit_cast(unsigned, f);
  unsigned r = (u + 0x7FFFu + ((u >> 16) & 1u)) >> 16;  // RNE
  return (short)r;
}

__device__ __forceinline__ unsigned cvt_pk_bf16(float lo, float hi) {
  unsigned r;
  asm volatile("v_cvt_pk_bf16_f32 %0, %1, %2" : "=v"(r) : "v"(lo), "v"(hi));
  return r;  // low16=bf16(lo), high16=bf16(hi)
}

__device__ __forceinline__ void gload16(const short* g, short* l) {
  __builtin_amdgcn_global_load_lds(
      (const __attribute__((address_space(1))) unsigned*)g,
      (__attribute__((address_space(3))) unsigned*)l, 16, 0, 0);
}

// ---------------- Kernel 0: W transpose+convert (unit-fragment-major) ----
// Wtb unit (kt 0..31, cf 0..11) at Wtb + (kt*12+cf)*512:
//   lane l (g=l>>4, lr=l&15) holds W_{wi}[kt*32+8g+j][n] for j=0..7,
//   wi = cf>>2, n = (cf&3)*16 + lr  (i.e. n_global = cf*16+lr).
__global__ __launch_bounds__(256) void wprep_kernel(
    const float* __restrict__ Wq, const float* __restrict__ Wk,
    const float* __restrict__ Wv, short* __restrict__ Wtb) {
  int lin = blockIdx.x * 256 + threadIdx.x;  // 24576 threads = 384 units x 64
  int l = lin & 63;
  int cf = (lin >> 6) % 12;
  int kt = lin / 768;
  int g = l >> 4, lr = l & 15;
  int wi = cf >> 2;
  int n = ((cf & 3) << 4) + lr;
  const float* W = (wi == 0) ? Wq : (wi == 1) ? Wk : Wv;
  short* dst = Wtb + (size_t)(kt * 12 + cf) * 512 + l * 8;
#pragma unroll
  for (int j = 0; j < 8; j++) dst[j] = f2bf(W[(kt * 32 + g * 8 + j) * 64 + n]);
}

// ---------------- Kernel 1: pipelined QKV projection ----------------
// 256 blocks x 512 thr (8 waves). M=64 rows/block, K-tile=32, ring-4 80KB.
// LDS tile = 20 units x 1KB:
//   u<8  : x units (f32), u = xwr*2 + h; lane l holds
//          x[m0+xwr*16+(l&15)][k0 + 8*(l>>4) + 4h .. +3]
//   u>=8 : W units (bf16), u = 8 + cf; linear 1KB copy of Wtb unit (kt,cf).
// Wave (wr=w&3, wc=w>>2): 16 rows x 96 cols, acc[6]. Both operands use the
// same within-tile k-bijection (k = 8g + j) -> contraction exact.
__device__ __forceinline__ void proj_stage(const float* __restrict__ x,
                                           const short* __restrict__ Wtb,
                                           short* dst, int m0, int k0, int w, int l) {
  const int g = l >> 4, lr = l & 15;
  if (w < 4) {
#pragma unroll
    for (int i = 0; i < 5; i++) {
      int u = w * 5 + i;
      if (u < 8) {
        int xwr = u >> 1, h = u & 1;
        const float* src = x + (size_t)(m0 + xwr * 16 + lr) * 1024 + k0 + g * 8 + h * 4;
        gload16((const short*)src, dst + u * 512);
      } else {
        int cf = u - 8;
        const short* src = Wtb + (size_t)((k0 >> 5) * 12 + cf) * 512 + l * 8;  // linear
        gload16(src, dst + u * 512);
      }
    }
  }
}

__device__ __forceinline__ void proj_compute(const short* __restrict__ ldsb,
                                             f32x4 (&acc)[6], int wr, int wc, int l) {
  f32x4 fa = *(const f32x4*)&ldsb[(wr * 2 + 0) * 512 + l * 8];  // k slots g*8+0..3
  f32x4 fb = *(const f32x4*)&ldsb[(wr * 2 + 1) * 512 + l * 8];  // k slots g*8+4..7
  uint4_t u_;
  u_[0] = cvt_pk_bf16(fa[0], fa[1]);
  u_[1] = cvt_pk_bf16(fa[2], fa[3]);
  u_[2] = cvt_pk_bf16(fb[0], fb[1]);
  u_[3] = cvt_pk_bf16(fb[2], fb[3]);
  short8 a = __builtin_bit_cast(short8, u_);
#pragma unroll
  for (int nf = 0; nf < 6; nf++) {
    int cf = wc * 6 + nf;
    short8 bfrag = *(const short8*)&ldsb[(8 + cf) * 512 + l * 8];
    acc[nf] = MFMA32(a, bfrag, acc[nf]);
  }
}

__global__ __launch_bounds__(512) void proj_kernel(
    const float* __restrict__ x, const short* __restrict__ Wtb,
    short* __restrict__ qb, short* __restrict__ kvb) {
  __shared__ __align__(16) short lds[4 * 20 * 512];  // 80KB ring-4
  const int tid = threadIdx.x;
  const int l = tid & 63, w = tid >> 6;
  const int g = l >> 4, lr = l & 15;
  const int wr = w & 3, wc = w >> 2;
  const int m0 = blockIdx.x * 64;

  f32x4 acc[6];
#pragma unroll
  for (int i = 0; i < 6; i++) acc[i] = (f32x4){0.f, 0.f, 0.f, 0.f};

  short* b0 = lds;
  short* b1 = lds + 10240;
  short* b2 = lds + 20480;
  short* b3 = lds + 30720;
  // prologue: 3 tiles in flight (15 loads/wave for w<4)
  proj_stage(x, Wtb, b0, m0, 0, w, l);
  proj_stage(x, Wtb, b1, m0, 32, w, l);
  proj_stage(x, Wtb, b2, m0, 64, w, l);

  for (int I = 0; I < 30; I++) {
    // outstanding/wave (w<4) at top: rem(I) + 5(I+1) + 5(I+2) ->
    // vmcnt(10) == tile I landed; never 0 mid-loop.
    asm volatile("s_waitcnt vmcnt(10)" ::: "memory");
    __builtin_amdgcn_s_barrier();
    __builtin_amdgcn_sched_barrier(0);
    if (I + 3 < 32) proj_stage(x, Wtb, b3, m0, (I + 3) * 32, w, l);
    proj_compute(b0, acc, wr, wc, l);
    short* t = b0; b0 = b1; b1 = b2; b2 = b3; b3 = t;
  }
  // I=30: only tile 31's 5 loads younger -> vmcnt(5) == tile 30 landed
  asm volatile("s_waitcnt vmcnt(5)" ::: "memory");
  __builtin_amdgcn_s_barrier();
  __builtin_amdgcn_sched_barrier(0);
  proj_compute(b0, acc, wr, wc, l);
  { short* t = b0; b0 = b1; b1 = b2; b2 = b3; b3 = t; }
  // I=31: drain
  asm volatile("s_waitcnt vmcnt(0)" ::: "memory");
  __builtin_amdgcn_s_barrier();
  __builtin_amdgcn_sched_barrier(0);
  proj_compute(b0, acc, wr, wc, l);

  // epilogue: verified store formulas (wave = 16 rows x 96 cols)
#pragma unroll
  for (int nf = 0; nf < 6; nf++) {
    int colg0 = wc * 96 + nf * 16;
    int wi = colg0 >> 6;
    int d = (colg0 & 63) + lr;
    // fold 1/sqrt(H)*log2(e) into q so attn softmax uses 2^x directly
    float scale = (wi == 0) ? 0.18033688f : 1.0f;
#pragma unroll
    for (int r = 0; r < 4; r++) {
      int row = m0 + wr * 16 + g * 4 + r;
      int b = row >> 11, t = row & 2047;
      short bv = f2bf(acc[nf][r] * scale);
      if (wi == 0) {
        int idx = (((b * 128 + (t >> 4)) * 2 + (d >> 5)) * 64 +
                   ((((d >> 3) & 3) << 4) | (t & 15))) * 8 + (d & 7);
        qb[idx] = bv;
      } else if (wi == 1) {
        int u = (b << 2) | (((t >> 4) & 1) << 1) | (d >> 5);
        int idx = (((t >> 5) * 64 + u) << 9) +
                  ((((((d >> 3) & 3) << 4)) | (t & 15)) << 3) + (d & 7);
        kvb[idx] = bv;
      } else {
        int u = 32 + (b << 2) + (d >> 4);
        int idx = (((t >> 5) * 64 + u) << 9) +
                  (((((t >> 2) & 3) << 4) | (d & 15)) << 3) + (((t >> 4) & 1) << 2) + (t & 3);
        kvb[idx] = bv;
      }
    }
  }
}

// ---------------- Kernel 2: pipelined fused attention ----------------
__device__ __forceinline__ void stage_step(const short* __restrict__ kvb,
                                           short* lds_buf, int w, int l, int W) {
#pragma unroll
  for (int i = 0; i < 8; i++) {
    int u = w * 8 + i;
    const short* src = kvb + (((size_t)W * 64 + u) << 9) + l * 8;
    gload16(src, lds_buf + u * 512);
  }
}

// 256 blocks x 512 thr = 8 waves: tt = w>>1 (4 t-tiles of 16), dh = w&1.
// Block: 64 t-rows x one 256-s chunk; 8 steps of 32 s. sc = xcd (lin&7).
__global__ __launch_bounds__(512, 2) void attn_kernel(
    const short* __restrict__ qb, const short* __restrict__ kvb,
    short* __restrict__ partial) {
  __shared__ __align__(16) short lds[2][64 * 512];  // 2 x 64KB ring
  const int tid = threadIdx.x;
  const int l = tid & 63, w = tid >> 6;
  const int tt = w >> 1, dh = w & 1;
  const int lin = blockIdx.x;     // 0..255
  const int sc = lin & 7;         // 0..7: per-XCD s-chunk of 256
  const int tblk = lin >> 3;      // 0..31
  const int tb16 = tblk * 4 + tt; // 0..127

  // Q hoisted: 16 x b128
  short8 qf[8][2];
#pragma unroll
  for (int b = 0; b < 8; b++)
#pragma unroll
    for (int ks = 0; ks < 2; ks++)
      qf[b][ks] = *(const short8*)&qb[(size_t)((b * 128 + tb16) * 2 + ks) * 512 + l * 8];

  f32x4 oacc[8][2];
#pragma unroll
  for (int b = 0; b < 8; b++)
#pragma unroll
    for (int n = 0; n < 2; n++) oacc[b][n] = (f32x4){0.f, 0.f, 0.f, 0.f};

  stage_step(kvb, &lds[0][0], w, l, sc * 8);

  for (int it = 0; it < 8; it++) {
    __syncthreads();  // drains step-old staging (free), publishes buf[it]
    if (it + 1 < 8) stage_step(kvb, &lds[(it + 1) & 1][0], w, l, sc * 8 + it + 1);
    const short* ldsc = &lds[it & 1][0];

    uint2_t plo[8], phi[8];
#pragma unroll
    for (int sf = 0; sf < 2; sf++) {
      f32x4 S[8];
      __builtin_amdgcn_s_setprio(1);
#pragma unroll
      for (int b = 0; b < 8; b++) {
        short8 kf0 = *(const short8*)&ldsc[(b * 4 + sf * 2 + 0) * 512 + l * 8];
        short8 kf1 = *(const short8*)&ldsc[(b * 4 + sf * 2 + 1) * 512 + l * 8];
        f32x4 s = (f32x4){0.f, 0.f, 0.f, 0.f};
        s = MFMA32(kf0, qf[b][0], s);
        s = MFMA32(kf1, qf[b][1], s);
        S[b] = s;
      }
      __builtin_amdgcn_s_setprio(0);
      // softmax over batch (elementwise across the 8 register sets)
#pragma unroll
      for (int r = 0; r < 4; r++) {
        float den = 0.f;
#pragma unroll
        for (int b = 0; b < 8; b++) {
          float e = __builtin_amdgcn_exp2f(S[b][r]);
          S[b][r] = e;
          den += e;
        }
        float inv = __builtin_amdgcn_rcpf(den);
#pragma unroll
        for (int b = 0; b < 8; b++) S[b][r] *= inv;
      }
#pragma unroll
      for (int b = 0; b < 8; b++) {
        uint2_t pw;
        pw[0] = cvt_pk_bf16(S[b][0], S[b][1]);
        pw[1] = cvt_pk_bf16(S[b][2], S[b][3]);
        if (sf == 0) plo[b] = pw; else phi[b] = pw;
      }
    }
    // PV k=32: A = V unit (16 d x 32 s, sigma-map), B = packed P
    __builtin_amdgcn_s_setprio(1);
#pragma unroll
    for (int b = 0; b < 8; b++) {
      uint4_t pu;
      pu[0] = plo[b][0]; pu[1] = plo[b][1]; pu[2] = phi[b][0]; pu[3] = phi[b][1];
      short8 pbv = __builtin_bit_cast(short8, pu);
      short8 vf0 = *(const short8*)&ldsc[(32 + b * 4 + dh * 2 + 0) * 512 + l * 8];
      short8 vf1 = *(const short8*)&ldsc[(32 + b * 4 + dh * 2 + 1) * 512 + l * 8];
      oacc[b][0] = MFMA32(vf0, pbv, oacc[b][0]);
      oacc[b][1] = MFMA32(vf1, pbv, oacc[b][1]);
    }
    __builtin_amdgcn_s_setprio(0);
  }

  // store bf16 partial fragment-major (uint2/lane, wave-contiguous 512B runs)
  uint2_t* pout = (uint2_t*)partial;
#pragma unroll
  for (int b = 0; b < 8; b++)
#pragma unroll
    for (int n = 0; n < 2; n++) {
      int df = dh * 2 + n;
      uint2_t pk;
      pk[0] = cvt_pk_bf16(oacc[b][n][0], oacc[b][n][1]);
      pk[1] = cvt_pk_bf16(oacc[b][n][2], oacc[b][n][3]);
      pout[(size_t)(((sc * 8 + b) * 128 + tb16) * 4 + df) * 64 + l] = pk;
    }
}

// ---------------- Kernel 3: reduce bf16 partials -> f32 out ----------------
__global__ __launch_bounds__(256) void reduce_kernel(const short* __restrict__ partial,
                                                     float* __restrict__ out) {
  int i = blockIdx.x * 256 + threadIdx.x;  // 0..262143: (b,tb16,df,l)
  const uint2_t* p = (const uint2_t*)partial;
  float4_t a = (float4_t){0.f, 0.f, 0.f, 0.f};
  for (int sc = 0; sc < 8; sc++) {
    uint2_t v = p[(size_t)sc * 262144 + i];  // plain load: L2/L3-served
    a[0] += __builtin_bit_cast(float, v[0] << 16);
    a[1] += __builtin_bit_cast(float, v[0] & 0xFFFF0000u);
    a[2] += __builtin_bit_cast(float, v[1] << 16);
    a[3] += __builtin_bit_cast(float, v[1] & 0xFFFF0000u);
  }
  int b = i >> 15;
  int r1 = i & 32767;
  int tb16 = r1 >> 8;
  int r2 = r1 & 255;
  int df = r2 >> 6;
  int ll = r2 & 63;
  int gg = ll >> 4, lrr = ll & 15;
  float4_t o = a;
  __builtin_nontemporal_store(
      o, (float4_t*)&out[(size_t)(b * 2048 + tb16 * 16 + lrr) * 64 + df * 16 + gg * 4]);
}

extern "C" void kernel_launch(void* const* d_in, const int* in_sizes, int n_in,
                              void* d_out, int out_size, void* d_ws, size_t ws_size,
                              hipStream_t stream) {
  const float* x = (const float*)d_in[0];
  const float* Wq = (const float*)d_in[1];
  const float* Wk = (const float*)d_in[2];
  const float* Wv = (const float*)d_in[3];
  float* out = (float*)d_out;

  char* ws = (char*)d_ws;
  short* qb = (short*)ws;                     // 2MB
  short* kvb = qb + 16384 * 64;               // 4MB (64 windows x 64 units)
  short* partial = kvb + 2 * 16384 * 64;      // 16MB bf16 fragment-major
  short* Wtb = partial + 8ull * 262144 * 4;   // 384KB (unit-fragment-major)

  wprep_kernel<<<96, 256, 0, stream>>>(Wq, Wk, Wv, Wtb);
  proj_kernel<<<256, 512, 0, stream>>>(x, Wtb, qb, kvb);
  attn_kernel<<<256, 512, 0, stream>>>(qb, kvb, partial);
  reduce_kernel<<<1024, 256, 0, stream>>>(partial, out);
}